// Round 1
// baseline (448.898 us; speedup 1.0000x reference)
//
#include <hip/hip_runtime.h>

// SuperLoRAGroup: out = FWHT24( G * Pi( FWHT24( pad( sign * vec(Bw@A)/16 ) ) ) )
// Key reduction: padded input nonzero only below 2^22 => FWHT1 output is
// periodic with period 2^22: y1[I] = W22[I & 0x3FFFFF] / 2^12, where W22 is the
// unnormalized 22-bit FWHT of the 16MB live input. Gather table = 16MB only.
//
// P1: GEMM+sign fused, FWHT over bits 0..13 per 16K chunk      -> ws (16MB)
// P2: FWHT over bits 14..21 (256-pt, stride 2^14), in-place on ws
// P3: z[j] = ws[perm[j]&0x3FFFFF]*G[j]*2^-24, FWHT bits 0..13  -> d_out (64MB)
// P4: FWHT over bits 14..23 (1024-pt, stride 2^14), in-place on d_out

#define THREADS 1024

constexpr float kScaling = 0.0625f;             // alpha/rank = 1/16
constexpr float kNorm = 5.9604644775390625e-8f; // 2^-24 (both 1/sqrt(2^24) factors)

__device__ __forceinline__ void fwht16(float r[16]) {
#pragma unroll
  for (int s = 1; s < 16; s <<= 1) {
#pragma unroll
    for (int i = 0; i < 16; i++) {
      if (!(i & s)) {
        float a = r[i];
        float b = r[i | s];
        r[i] = a + b;
        r[i | s] = a - b;
      }
    }
  }
}

__device__ __forceinline__ float4 f4_add(float4 a, float4 b) {
  return make_float4(a.x + b.x, a.y + b.y, a.z + b.z, a.w + b.w);
}
__device__ __forceinline__ float4 f4_sub(float4 a, float4 b) {
  return make_float4(a.x - b.x, a.y - b.y, a.z - b.z, a.w - b.w);
}

// FWHT over the 14 low bits of a 16384-float LDS tile (radix 16/16/16/4).
// Final round streams results straight to dst4 (global chunk base, float4).
// Caller must __syncthreads() after filling lds.
__device__ __forceinline__ void fwht_lo_rounds(float* lds, int t, float4* dst4) {
  float4* lds4 = (float4*)lds;
  // bits 0..3: 16 contiguous floats per thread (4x ds_read_b128, 2-way max)
  {
    float r[16];
#pragma unroll
    for (int q = 0; q < 4; q++) {
      float4 v = lds4[t * 4 + q];
      r[4 * q + 0] = v.x;
      r[4 * q + 1] = v.y;
      r[4 * q + 2] = v.z;
      r[4 * q + 3] = v.w;
    }
    fwht16(r);
#pragma unroll
    for (int q = 0; q < 4; q++)
      lds4[t * 4 + q] =
          make_float4(r[4 * q + 0], r[4 * q + 1], r[4 * q + 2], r[4 * q + 3]);
  }
  __syncthreads();
  // bits 4..7 (b32 stride 16; known ~4-way conflict, accepted in v1)
  {
    const int c = (t & 15) | ((t >> 4) << 8);
    float r[16];
#pragma unroll
    for (int k = 0; k < 16; k++) r[k] = lds[c + (k << 4)];
    fwht16(r);
#pragma unroll
    for (int k = 0; k < 16; k++) lds[c + (k << 4)] = r[k];
  }
  __syncthreads();
  // bits 8..11 (b32 stride 256; banks = t&31 -> 2-way, free)
  {
    const int c = (t & 255) | ((t >> 8) << 12);
    float r[16];
#pragma unroll
    for (int k = 0; k < 16; k++) r[k] = lds[c + (k << 8)];
    fwht16(r);
#pragma unroll
    for (int k = 0; k < 16; k++) lds[c + (k << 8)] = r[k];
  }
  __syncthreads();
  // bits 12..13 (radix-4 on float4 payload) fused with global store
  {
    float4 v0 = lds4[t + 0 * 1024];
    float4 v1 = lds4[t + 1 * 1024];
    float4 v2 = lds4[t + 2 * 1024];
    float4 v3 = lds4[t + 3 * 1024];
    float4 e0 = f4_add(v0, v1), e1 = f4_sub(v0, v1);
    float4 e2 = f4_add(v2, v3), e3 = f4_sub(v2, v3);
    dst4[t + 0 * 1024] = f4_add(e0, e2);
    dst4[t + 1 * 1024] = f4_add(e1, e3);
    dst4[t + 2 * 1024] = f4_sub(e0, e2);
    dst4[t + 3 * 1024] = f4_sub(e1, e3);
  }
}

// P1: delta=(Bw@A)*1/16, *sign, FWHT bits0..13 -> W. 256 blocks (chunks of 2^14).
__global__ __launch_bounds__(THREADS) void k1_build_fwht_lo(
    const float* __restrict__ A, const float* __restrict__ Bw,
    const float* __restrict__ sgn, float* __restrict__ W) {
  __shared__ float lds[16384];
  const int t = threadIdx.x;
  const int blk = blockIdx.x; // 0..255
  const unsigned base = (unsigned)blk << 14;

  // GEMM fill: chunk covers rows r0..r0+7 (all 2048 cols). Each thread: 2 cols.
  float a0[16], a1[16];
#pragma unroll
  for (int k = 0; k < 16; k++) {
    a0[k] = A[k * 2048 + t];
    a1[k] = A[k * 2048 + t + 1024];
  }
  const int r0 = blk * 8;
#pragma unroll
  for (int rl = 0; rl < 8; rl++) {
    float s0 = 0.f, s1 = 0.f;
#pragma unroll
    for (int k = 0; k < 16; k++) {
      float b = Bw[(r0 + rl) * 16 + k]; // uniform -> scalar load
      s0 += b * a0[k];
      s1 += b * a1[k];
    }
    const int l0 = rl * 2048 + t;
    const int l1 = l0 + 1024;
    lds[l0] = s0 * kScaling * sgn[base + l0];
    lds[l1] = s1 * kScaling * sgn[base + l1];
  }
  __syncthreads();
  fwht_lo_rounds(lds, t, (float4*)W + ((unsigned)blk << 12));
}

// P2: 256-pt FWHT over chunk index (bits 14..21), in-place on W.
// Tile: 64 float cols (16 float4) x 256 rows. 256 blocks.
__global__ __launch_bounds__(THREADS) void k2_fwht_mid(float* __restrict__ W) {
  __shared__ float lds[16384];
  float4* lds4 = (float4*)lds;
  const int t = threadIdx.x;
  const int c0 = blockIdx.x * 16; // float4-column base
  float4* W4 = (float4*)W;        // 256 rows x 4096 f4-cols
#pragma unroll
  for (int m = 0; m < 4; m++) {
    const int idx4 = t + THREADS * m;
    const int row = idx4 >> 4, c4 = idx4 & 15;
    lds4[idx4] = W4[row * 4096 + c0 + c4]; // 256B/row segments
  }
  __syncthreads();
  const int c4 = t & 15;
  const int f = t >> 4; // 0..63
#pragma unroll
  for (int r = 0; r < 4; r++) {
    const int m = 1 << (2 * r);
    int rows[4];
#pragma unroll
    for (int k2 = 0; k2 < 4; k2++)
      rows[k2] = (f & (m - 1)) + k2 * m + (f >> (2 * r)) * (m << 2);
    float4 v0 = lds4[rows[0] * 16 + c4];
    float4 v1 = lds4[rows[1] * 16 + c4];
    float4 v2 = lds4[rows[2] * 16 + c4];
    float4 v3 = lds4[rows[3] * 16 + c4];
    float4 e0 = f4_add(v0, v1), e1 = f4_sub(v0, v1);
    float4 e2 = f4_add(v2, v3), e3 = f4_sub(v2, v3);
    float4 o0 = f4_add(e0, e2), o1 = f4_add(e1, e3);
    float4 o2 = f4_sub(e0, e2), o3 = f4_sub(e1, e3);
    if (r < 3) {
      lds4[rows[0] * 16 + c4] = o0;
      lds4[rows[1] * 16 + c4] = o1;
      lds4[rows[2] * 16 + c4] = o2;
      lds4[rows[3] * 16 + c4] = o3;
      __syncthreads();
    } else {
      W4[rows[0] * 4096 + c0 + c4] = o0;
      W4[rows[1] * 4096 + c0 + c4] = o1;
      W4[rows[2] * 4096 + c0 + c4] = o2;
      W4[rows[3] * 4096 + c0 + c4] = o3;
    }
  }
}

// P3: z = W[perm&mask]*G*2^-24, FWHT bits0..13 -> out. 1024 blocks.
__global__ __launch_bounds__(THREADS) void k3_perm_fwht_lo(
    const float* __restrict__ W, const int* __restrict__ perm,
    const float* __restrict__ G, float* __restrict__ out) {
  __shared__ float lds[16384];
  float4* lds4 = (float4*)lds;
  const int t = threadIdx.x;
  const unsigned base4 = (unsigned)blockIdx.x << 12;
  const int4* P4 = (const int4*)perm + base4;
  const float4* G4 = (const float4*)G + base4;
#pragma unroll
  for (int m = 0; m < 4; m++) {
    const int idx4 = t + THREADS * m;
    const int4 p = P4[idx4];
    const float4 g = G4[idx4];
    float4 v;
    v.x = W[p.x & 0x3FFFFF] * (g.x * kNorm);
    v.y = W[p.y & 0x3FFFFF] * (g.y * kNorm);
    v.z = W[p.z & 0x3FFFFF] * (g.z * kNorm);
    v.w = W[p.w & 0x3FFFFF] * (g.w * kNorm);
    lds4[idx4] = v;
  }
  __syncthreads();
  fwht_lo_rounds(lds, t, (float4*)out + base4);
}

// P4: 1024-pt FWHT over bits 14..23, in-place on out.
// Tile: 16 float cols (4 float4) x 1024 rows; hi-row XOR swizzle for banks.
__global__ __launch_bounds__(THREADS) void k4_fwht_hi(float* __restrict__ out) {
  __shared__ float lds[16384];
  float4* lds4 = (float4*)lds;
  const int t = threadIdx.x;
  const int c0 = blockIdx.x * 4; // float4-column base
  float4* O4 = (float4*)out;     // 1024 rows x 4096 f4-cols
#pragma unroll
  for (int m = 0; m < 4; m++) {
    const int idx4 = t + THREADS * m;
    const int hi = idx4 >> 2, c4 = idx4 & 3;
    const int his = hi ^ ((hi >> 4) & 1); // bank swizzle (involution)
    lds4[his * 4 + c4] = O4[(unsigned)hi * 4096 + c0 + c4];
  }
  __syncthreads();
  const int c4 = t & 3;
  const int f = t >> 2; // 0..255
#pragma unroll
  for (int r = 0; r < 5; r++) {
    const int m = 1 << (2 * r);
    int hi_[4], his_[4];
#pragma unroll
    for (int k2 = 0; k2 < 4; k2++) {
      hi_[k2] = (f & (m - 1)) + k2 * m + (f >> (2 * r)) * (m << 2);
      his_[k2] = hi_[k2] ^ ((hi_[k2] >> 4) & 1);
    }
    float4 v0 = lds4[his_[0] * 4 + c4];
    float4 v1 = lds4[his_[1] * 4 + c4];
    float4 v2 = lds4[his_[2] * 4 + c4];
    float4 v3 = lds4[his_[3] * 4 + c4];
    float4 e0 = f4_add(v0, v1), e1 = f4_sub(v0, v1);
    float4 e2 = f4_add(v2, v3), e3 = f4_sub(v2, v3);
    float4 o0 = f4_add(e0, e2), o1 = f4_add(e1, e3);
    float4 o2 = f4_sub(e0, e2), o3 = f4_sub(e1, e3);
    if (r < 4) {
      lds4[his_[0] * 4 + c4] = o0;
      lds4[his_[1] * 4 + c4] = o1;
      lds4[his_[2] * 4 + c4] = o2;
      lds4[his_[3] * 4 + c4] = o3;
      __syncthreads();
    } else {
      O4[(unsigned)hi_[0] * 4096 + c0 + c4] = o0;
      O4[(unsigned)hi_[1] * 4096 + c0 + c4] = o1;
      O4[(unsigned)hi_[2] * 4096 + c0 + c4] = o2;
      O4[(unsigned)hi_[3] * 4096 + c0 + c4] = o3;
    }
  }
}

extern "C" void kernel_launch(void* const* d_in, const int* in_sizes, int n_in,
                              void* d_out, int out_size, void* d_ws,
                              size_t ws_size, hipStream_t stream) {
  (void)in_sizes;
  (void)n_in;
  (void)out_size;
  (void)ws_size;
  const float* A = (const float*)d_in[0];    // (16, 2048)
  const float* Bw = (const float*)d_in[1];   // (2048, 16)
  const float* G = (const float*)d_in[2];    // (2^24,)
  const float* sgn = (const float*)d_in[3];  // (2^24,)
  const int* perm = (const int*)d_in[4];     // (2^24,) int32
  float* out = (float*)d_out;                // (2^24,) f32
  float* W = (float*)d_ws;                   // 2^22 floats = 16MB scratch

  k1_build_fwht_lo<<<256, THREADS, 0, stream>>>(A, Bw, sgn, W);
  k2_fwht_mid<<<256, THREADS, 0, stream>>>(W);
  k3_perm_fwht_lo<<<1024, THREADS, 0, stream>>>(W, perm, G, out);
  k4_fwht_hi<<<1024, THREADS, 0, stream>>>(out);
}

// Round 2
// 361.654 us; speedup vs baseline: 1.2412x; 1.2412x over previous
//
#include <hip/hip_runtime.h>

// SuperLoRAGroup: out = FWHT24( G * Pi( FWHT24( pad( sign * vec(Bw@A)/16 ) ) ) )
// FWHT1 output periodic with period 2^22 => gather table W = 16MB only.
//
// P1 : GEMM+sign fused, FWHT bits 0..13 per 16K chunk            -> ws (16MB)
// P2 : FWHT bits 14..21 (256-pt, stride 2^14), in-place on ws    (k_fwht_mid)
// P3 : z[j] = ws[perm[j]&m]*G[j]*2^-24, FWHT bits 0..13          -> d_out
//      gathers phase-partitioned into 4x 4MB W-quarters so the gather
//      working set stays L2-resident; perm/G/out are nontemporal.
// P4a: FWHT bits 14..21 per 2^22 segment, in-place on d_out      (k_fwht_mid)
// P4b: FWHT bits 22..23 (radix-4, stride 2^22), fully coalesced.

#define THREADS 1024

typedef float vf4 __attribute__((ext_vector_type(4)));
typedef int vi4 __attribute__((ext_vector_type(4)));

constexpr float kScaling = 0.0625f;             // alpha/rank = 1/16
constexpr float kNorm = 5.9604644775390625e-8f; // 2^-24 (both fwht norms)

__device__ __forceinline__ void fwht16(float r[16]) {
#pragma unroll
  for (int s = 1; s < 16; s <<= 1) {
#pragma unroll
    for (int i = 0; i < 16; i++) {
      if (!(i & s)) {
        float a = r[i];
        float b = r[i | s];
        r[i] = a + b;
        r[i | s] = a - b;
      }
    }
  }
}

// FWHT over the 14 low bits of a 16384-float LDS tile (radix 16/16/16/4).
// Final round streams results straight to dst4. Caller syncs after fill.
template <bool NT>
__device__ __forceinline__ void fwht_lo_rounds(float* lds, int t, vf4* dst4) {
  vf4* lds4 = (vf4*)lds;
  // bits 0..3: 16 contiguous floats per thread
  {
    float r[16];
#pragma unroll
    for (int q = 0; q < 4; q++) {
      vf4 v = lds4[t * 4 + q];
#pragma unroll
      for (int c = 0; c < 4; c++) r[4 * q + c] = v[c];
    }
    fwht16(r);
#pragma unroll
    for (int q = 0; q < 4; q++) {
      vf4 v;
#pragma unroll
      for (int c = 0; c < 4; c++) v[c] = r[4 * q + c];
      lds4[t * 4 + q] = v;
    }
  }
  __syncthreads();
  // bits 4..7 (b32 stride 16)
  {
    const int c = (t & 15) | ((t >> 4) << 8);
    float r[16];
#pragma unroll
    for (int k = 0; k < 16; k++) r[k] = lds[c + (k << 4)];
    fwht16(r);
#pragma unroll
    for (int k = 0; k < 16; k++) lds[c + (k << 4)] = r[k];
  }
  __syncthreads();
  // bits 8..11 (b32 stride 256)
  {
    const int c = (t & 255) | ((t >> 8) << 12);
    float r[16];
#pragma unroll
    for (int k = 0; k < 16; k++) r[k] = lds[c + (k << 8)];
    fwht16(r);
#pragma unroll
    for (int k = 0; k < 16; k++) lds[c + (k << 8)] = r[k];
  }
  __syncthreads();
  // bits 12..13 (radix-4 on float4 payload) fused with global store
  {
    vf4 v0 = lds4[t + 0 * 1024];
    vf4 v1 = lds4[t + 1 * 1024];
    vf4 v2 = lds4[t + 2 * 1024];
    vf4 v3 = lds4[t + 3 * 1024];
    vf4 e0 = v0 + v1, e1 = v0 - v1;
    vf4 e2 = v2 + v3, e3 = v2 - v3;
    vf4 o0 = e0 + e2, o1 = e1 + e3, o2 = e0 - e2, o3 = e1 - e3;
    if (NT) {
      __builtin_nontemporal_store(o0, &dst4[t + 0 * 1024]);
      __builtin_nontemporal_store(o1, &dst4[t + 1 * 1024]);
      __builtin_nontemporal_store(o2, &dst4[t + 2 * 1024]);
      __builtin_nontemporal_store(o3, &dst4[t + 3 * 1024]);
    } else {
      dst4[t + 0 * 1024] = o0;
      dst4[t + 1 * 1024] = o1;
      dst4[t + 2 * 1024] = o2;
      dst4[t + 3 * 1024] = o3;
    }
  }
}

// P1: delta=(Bw@A)/16, *sign, FWHT bits0..13 -> W. 256 blocks.
__global__ __launch_bounds__(THREADS) void k1_build_fwht_lo(
    const float* __restrict__ A, const float* __restrict__ Bw,
    const float* __restrict__ sgn, float* __restrict__ W) {
  __shared__ float lds[16384];
  const int t = threadIdx.x;
  const int blk = blockIdx.x;
  const unsigned base = (unsigned)blk << 14;

  float a0[16], a1[16];
#pragma unroll
  for (int k = 0; k < 16; k++) {
    a0[k] = A[k * 2048 + t];
    a1[k] = A[k * 2048 + t + 1024];
  }
  const int r0 = blk * 8;
#pragma unroll
  for (int rl = 0; rl < 8; rl++) {
    float s0 = 0.f, s1 = 0.f;
#pragma unroll
    for (int k = 0; k < 16; k++) {
      float b = Bw[(r0 + rl) * 16 + k];
      s0 += b * a0[k];
      s1 += b * a1[k];
    }
    const int l0 = rl * 2048 + t;
    const int l1 = l0 + 1024;
    lds[l0] = s0 * kScaling * sgn[base + l0];
    lds[l1] = s1 * kScaling * sgn[base + l1];
  }
  __syncthreads();
  fwht_lo_rounds<false>(lds, t, (vf4*)W + ((unsigned)blk << 12));
}

// 256-pt FWHT over bits 14..21 within a 2^22-float segment, in-place.
// Grid = n_segments*256; seg = blockIdx>>8, col-tile = blockIdx&255.
__global__ __launch_bounds__(THREADS) void k_fwht_mid(float* __restrict__ buf) {
  __shared__ float lds[16384];
  vf4* lds4 = (vf4*)lds;
  const int t = threadIdx.x;
  const int seg = blockIdx.x >> 8;
  const int c0 = (blockIdx.x & 255) * 16; // float4-column base
  vf4* B4 = (vf4*)buf + ((unsigned)seg << 20); // 256 rows x 4096 f4-cols
#pragma unroll
  for (int m = 0; m < 4; m++) {
    const int idx4 = t + THREADS * m;
    const int row = idx4 >> 4, c4 = idx4 & 15;
    lds4[idx4] = B4[row * 4096 + c0 + c4]; // 256B/row segments
  }
  __syncthreads();
  const int c4 = t & 15;
  const int f = t >> 4; // 0..63
#pragma unroll
  for (int r = 0; r < 4; r++) {
    const int m = 1 << (2 * r);
    int rows[4];
#pragma unroll
    for (int k2 = 0; k2 < 4; k2++)
      rows[k2] = (f & (m - 1)) + k2 * m + (f >> (2 * r)) * (m << 2);
    vf4 v0 = lds4[rows[0] * 16 + c4];
    vf4 v1 = lds4[rows[1] * 16 + c4];
    vf4 v2 = lds4[rows[2] * 16 + c4];
    vf4 v3 = lds4[rows[3] * 16 + c4];
    vf4 e0 = v0 + v1, e1 = v0 - v1;
    vf4 e2 = v2 + v3, e3 = v2 - v3;
    vf4 o0 = e0 + e2, o1 = e1 + e3, o2 = e0 - e2, o3 = e1 - e3;
    if (r < 3) {
      lds4[rows[0] * 16 + c4] = o0;
      lds4[rows[1] * 16 + c4] = o1;
      lds4[rows[2] * 16 + c4] = o2;
      lds4[rows[3] * 16 + c4] = o3;
      __syncthreads();
    } else {
      B4[rows[0] * 4096 + c0 + c4] = o0;
      B4[rows[1] * 4096 + c0 + c4] = o1;
      B4[rows[2] * 4096 + c0 + c4] = o2;
      B4[rows[3] * 4096 + c0 + c4] = o3;
    }
  }
}

// P3: z = W[perm&mask]*G*2^-24, FWHT bits0..13 -> out. 1024 blocks.
// Gathers phase-partitioned into 4x 4MB quarters of W for L2 residency.
__global__ __launch_bounds__(THREADS) void k3_perm_fwht_lo(
    const float* __restrict__ W, const int* __restrict__ perm,
    const float* __restrict__ G, float* __restrict__ out) {
  __shared__ float lds[16384];
  const int t = threadIdx.x;
  const unsigned base4 = (unsigned)blockIdx.x << 12;
  const vi4* P4 = (const vi4*)perm + base4;
  const vf4* G4 = (const vf4*)G + base4;
  int src[16];
  float gg[16];
#pragma unroll
  for (int m = 0; m < 4; m++) {
    const int idx4 = t + THREADS * m;
    vi4 p = __builtin_nontemporal_load(&P4[idx4]);
    vf4 g = __builtin_nontemporal_load(&G4[idx4]);
#pragma unroll
    for (int c = 0; c < 4; c++) {
      src[4 * m + c] = p[c] & 0x3FFFFF;
      gg[4 * m + c] = g[c] * kNorm;
    }
  }
#pragma unroll
  for (int pass = 0; pass < 4; pass++) {
#pragma unroll
    for (int s = 0; s < 16; s++) {
      if ((src[s] >> 20) == pass) {
        lds[4 * (t + THREADS * (s >> 2)) + (s & 3)] = W[src[s]] * gg[s];
      }
    }
    __syncthreads(); // keep resident blocks phase-aligned on the same quarter
  }
  fwht_lo_rounds<true>(lds, t, (vf4*)out + base4);
}

// P4b: radix-4 FWHT over bits 22..23 (stride 2^22), fully coalesced streams.
__global__ __launch_bounds__(THREADS) void k4b_fwht_top(float* __restrict__ out) {
  const unsigned idx4 = blockIdx.x * THREADS + threadIdx.x; // 0..2^20
  vf4* O4 = (vf4*)out;
  vf4 v0 = O4[idx4 + 0u * (1u << 20)];
  vf4 v1 = O4[idx4 + 1u * (1u << 20)];
  vf4 v2 = O4[idx4 + 2u * (1u << 20)];
  vf4 v3 = O4[idx4 + 3u * (1u << 20)];
  vf4 e0 = v0 + v1, e1 = v0 - v1;
  vf4 e2 = v2 + v3, e3 = v2 - v3;
  O4[idx4 + 0u * (1u << 20)] = e0 + e2;
  O4[idx4 + 1u * (1u << 20)] = e1 + e3;
  O4[idx4 + 2u * (1u << 20)] = e0 - e2;
  O4[idx4 + 3u * (1u << 20)] = e1 - e3;
}

extern "C" void kernel_launch(void* const* d_in, const int* in_sizes, int n_in,
                              void* d_out, int out_size, void* d_ws,
                              size_t ws_size, hipStream_t stream) {
  (void)in_sizes;
  (void)n_in;
  (void)out_size;
  (void)ws_size;
  const float* A = (const float*)d_in[0];   // (16, 2048)
  const float* Bw = (const float*)d_in[1];  // (2048, 16)
  const float* G = (const float*)d_in[2];   // (2^24,)
  const float* sgn = (const float*)d_in[3]; // (2^24,)
  const int* perm = (const int*)d_in[4];    // (2^24,) int32
  float* out = (float*)d_out;               // (2^24,) f32
  float* W = (float*)d_ws;                  // 2^22 floats = 16MB scratch

  k1_build_fwht_lo<<<256, THREADS, 0, stream>>>(A, Bw, sgn, W);
  k_fwht_mid<<<256, THREADS, 0, stream>>>(W);            // P2 on ws
  k3_perm_fwht_lo<<<1024, THREADS, 0, stream>>>(W, perm, G, out);
  k_fwht_mid<<<1024, THREADS, 0, stream>>>(out);         // P4a per segment
  k4b_fwht_top<<<1024, THREADS, 0, stream>>>(out);       // P4b top bits
}